// Round 9
// baseline (65.977 us; speedup 1.0000x reference)
//
#include <hip/hip_runtime.h>
#include <stddef.h>

// NPDCLoss: out[d] = mean_t (x_pred[t,d] - delayed_avg[t,d])^2
//   delayed_avg[t] = (sum_{j=1..m} x_true[t-j] + (NLAG-m)*x_true[t]) / NLAG
// Lag-50 window in 50 NAMED scalar registers (SROA -> VGPRs, no scratch/LDS).
// Ring slot for within-chunk hot row i is i%50, so any chunk start works; hot
// length just needs to be a multiple of 10 (C10 batches cycle RL0..RL4).

#define NS   16384
#define D    2048
#define NLAG 50

#define BLOCK 256
#define COLB  (D / BLOCK)      // 8 column blocks
#define CHUNK 100              // rows per chunk
#define RC    164              // 163 full chunks + last chunk of 84 rows

#define DD ((size_t)D)
#define NT(p) __builtin_nontemporal_load(p)

// ---- the 50-register ring, addressed only by name ----
#define RING_DECL \
    float R00,R01,R02,R03,R04,R05,R06,R07,R08,R09, \
          R10,R11,R12,R13,R14,R15,R16,R17,R18,R19, \
          R20,R21,R22,R23,R24,R25,R26,R27,R28,R29, \
          R30,R31,R32,R33,R34,R35,R36,R37,R38,R39, \
          R40,R41,R42,R43,R44,R45,R46,R47,R48,R49;

#define RL0 R00,R01,R02,R03,R04,R05,R06,R07,R08,R09
#define RL1 R10,R11,R12,R13,R14,R15,R16,R17,R18,R19
#define RL2 R20,R21,R22,R23,R24,R25,R26,R27,R28,R29
#define RL3 R30,R31,R32,R33,R34,R35,R36,R37,R38,R39
#define RL4 R40,R41,R42,R43,R44,R45,R46,R47,R48,R49

#define STEPC(pv, cv, R) { float e = (pv) - w * inv_n; acc += e * e; w += (cv) - (R); (R) = (cv); }

// one 10-row batch: 20 loads issued, then 10 compute steps; advances trow
#define C10_IMPL(Ra,Rb,Rc,Rd,Re,Rf,Rg,Rh,Ri,Rj) do { \
    const float* rp = xtc + (size_t)trow * DD; \
    const float* pp = xpc + (size_t)trow * DD; \
    float c0=rp[0*DD], c1=rp[1*DD], c2=rp[2*DD], c3=rp[3*DD], c4=rp[4*DD], \
          c5=rp[5*DD], c6=rp[6*DD], c7=rp[7*DD], c8=rp[8*DD], c9=rp[9*DD]; \
    float p0=NT(pp+0*DD), p1=NT(pp+1*DD), p2=NT(pp+2*DD), p3=NT(pp+3*DD), p4=NT(pp+4*DD), \
          p5=NT(pp+5*DD), p6=NT(pp+6*DD), p7=NT(pp+7*DD), p8=NT(pp+8*DD), p9=NT(pp+9*DD); \
    STEPC(p0,c0,Ra) STEPC(p1,c1,Rb) STEPC(p2,c2,Rc) STEPC(p3,c3,Rd) STEPC(p4,c4,Re) \
    STEPC(p5,c5,Rf) STEPC(p6,c6,Rg) STEPC(p7,c7,Rh) STEPC(p8,c8,Ri) STEPC(p9,c9,Rj) \
    trow += 10; \
} while (0)
#define C10(...) C10_IMPL(__VA_ARGS__)

#define WARM0(t, R) { float cv = xtc[(size_t)(t)*DD]; float pv = xpc[(size_t)(t)*DD]; \
    float e = pv - (w + (float)(NLAG-(t)) * cv) * inv_n; acc += e * e; w += cv; (R) = cv; }

#define WARMU(j, R) { float v = wsrc[(size_t)(j)*DD]; w += v; (R) = v; }

#define DO50(M) \
    M(0,R00) M(1,R01) M(2,R02) M(3,R03) M(4,R04) M(5,R05) M(6,R06) M(7,R07) M(8,R08) M(9,R09) \
    M(10,R10) M(11,R11) M(12,R12) M(13,R13) M(14,R14) M(15,R15) M(16,R16) M(17,R17) M(18,R18) M(19,R19) \
    M(20,R20) M(21,R21) M(22,R22) M(23,R23) M(24,R24) M(25,R25) M(26,R26) M(27,R27) M(28,R28) M(29,R29) \
    M(30,R30) M(31,R31) M(32,R32) M(33,R33) M(34,R34) M(35,R35) M(36,R36) M(37,R37) M(38,R38) M(39,R39) \
    M(40,R40) M(41,R41) M(42,R42) M(43,R43) M(44,R44) M(45,R45) M(46,R46) M(47,R47) M(48,R48) M(49,R49)

template <bool USE_WS>
__global__ __launch_bounds__(BLOCK, 4) void npdc_reg(
    const float* __restrict__ xp,
    const float* __restrict__ xt,
    float* __restrict__ partial,   // [RC][D] when USE_WS
    float* __restrict__ out)       // [D] atomic path when !USE_WS
{
    const int tid = (int)threadIdx.x;
    const int col = blockIdx.x * BLOCK + tid;
    const int rc  = blockIdx.y;
    const int r0  = rc * CHUNK;
    const int rows = (r0 + CHUNK <= NS) ? CHUNK : (NS - r0);
    const float inv_n = 1.0f / (float)NLAG;

    const float* xtc = xt + col;
    const float* xpc = xp + col;

    RING_DECL
    float w = 0.f, acc = 0.f;
    int trow, hot;

    if (rc == 0) {
        // rows 0..49: growing window (m = t); fills ring slots 0..49
        DO50(WARM0)
        trow = NLAG;
        hot  = rows - NLAG;
    } else {
        // warm-up: rows r0-50 .. r0-1 -> slots 0..49
        const float* wsrc = xtc + (size_t)(r0 - NLAG) * DD;
        DO50(WARMU)
        trow = r0;
        hot  = rows;
    }

    // ---- hot loop: slot of hot row i is i%50; batches of 10 cycle RL0..RL4.
    const int nfull = hot / NLAG;            // full 50-row groups
    const int rem10 = (hot % NLAG) / 10;     // remainder 10-row batches (0..4)
    const int tailn = hot % 10;              // leftover rows (<10)
    for (int g = 0; g < nfull; ++g) {
        C10(RL0); C10(RL1); C10(RL2); C10(RL3); C10(RL4);
    }
    if (rem10 > 0) C10(RL0);
    if (rem10 > 1) C10(RL1);
    if (rem10 > 2) C10(RL2);
    if (rem10 > 3) C10(RL3);

    // ---- tail (<10 rows, last chunk only): old value from global ----
    for (int k = 0; k < tailn; ++k, ++trow) {
        float cv = xtc[(size_t)trow * DD];
        float pv = xpc[(size_t)trow * DD];
        float ov = xtc[(size_t)(trow - NLAG) * DD];
        float e  = pv - w * inv_n;
        acc += e * e;
        w += cv - ov;
    }

    if (USE_WS) {
        partial[(size_t)rc * DD + col] = acc;
    } else {
        atomicAdd(&out[col], acc * (1.0f / (float)NS));
    }
}

// Reduce [RC][D] -> [D].  Grid: D/64 blocks of 256 threads.
__global__ __launch_bounds__(BLOCK) void npdc_reduce(
    const float* __restrict__ partial, float* __restrict__ out)
{
    const int dl = (int)threadIdx.x & 63;
    const int g  = (int)threadIdx.x >> 6;          // 0..3
    const int d  = blockIdx.x * 64 + dl;
    const int c0 = g * 41;
    const int c1 = (c0 + 41 < RC) ? c0 + 41 : RC;

    float s = 0.0f;
    for (int c = c0; c < c1; ++c)
        s += partial[(size_t)c * DD + d];

    __shared__ float sm[4][64];
    sm[g][dl] = s;
    __syncthreads();
    if (g == 0) {
        float t = sm[0][dl] + sm[1][dl] + sm[2][dl] + sm[3][dl];
        out[d] = t * (1.0f / (float)NS);
    }
}

__global__ __launch_bounds__(BLOCK) void npdc_zero(float* __restrict__ out)
{
    const int d = blockIdx.x * BLOCK + (int)threadIdx.x;
    if (d < D) out[d] = 0.0f;
}

extern "C" void kernel_launch(void* const* d_in, const int* in_sizes, int n_in,
                              void* d_out, int out_size, void* d_ws, size_t ws_size,
                              hipStream_t stream)
{
    const float* xp = (const float*)d_in[0];   // x_pred [NS, D]
    const float* xt = (const float*)d_in[1];   // x_true [NS, D]
    float* out = (float*)d_out;                // [D]

    const size_t ws_needed = (size_t)RC * D * sizeof(float);
    dim3 grid(COLB, RC);

    if (ws_size >= ws_needed) {
        float* partial = (float*)d_ws;
        npdc_reg<true><<<grid, BLOCK, 0, stream>>>(xp, xt, partial, out);
        npdc_reduce<<<D / 64, BLOCK, 0, stream>>>(partial, out);
    } else {
        npdc_zero<<<(D + BLOCK - 1) / BLOCK, BLOCK, 0, stream>>>(out);
        npdc_reg<false><<<grid, BLOCK, 0, stream>>>(xp, xt, nullptr, out);
    }
}

// Round 10
// 58.849 us; speedup vs baseline: 1.1211x; 1.1211x over previous
//
#include <hip/hip_runtime.h>
#include <stddef.h>

// NPDCLoss: out[d] = mean_t (x_pred[t,d] - delayed_avg[t,d])^2
//   delayed_avg[t] = (sum_{j=1..m} x_true[t-j] + (NLAG-m)*x_true[t]) / NLAG
// Lag-50 window in 50 NAMED registers; hot loop is an explicit 2-stage
// software pipeline (named stage regs A/B, 40 loads in flight per wave).

#define NS   16384
#define D    2048
#define NLAG 50

#define BLOCK 256
#define COLB  (D / BLOCK)      // 8 column blocks
#define CHUNK 150              // rows per chunk
#define RC    110              // 109 full chunks + last chunk of 34 rows

#define DD ((size_t)D)
#define NT(p) __builtin_nontemporal_load(p)

// ---- the 50-register ring ----
#define RING_DECL \
    float R00,R01,R02,R03,R04,R05,R06,R07,R08,R09, \
          R10,R11,R12,R13,R14,R15,R16,R17,R18,R19, \
          R20,R21,R22,R23,R24,R25,R26,R27,R28,R29, \
          R30,R31,R32,R33,R34,R35,R36,R37,R38,R39, \
          R40,R41,R42,R43,R44,R45,R46,R47,R48,R49;

#define RL0 R00,R01,R02,R03,R04,R05,R06,R07,R08,R09
#define RL1 R10,R11,R12,R13,R14,R15,R16,R17,R18,R19
#define RL2 R20,R21,R22,R23,R24,R25,R26,R27,R28,R29
#define RL3 R30,R31,R32,R33,R34,R35,R36,R37,R38,R39
#define RL4 R40,R41,R42,R43,R44,R45,R46,R47,R48,R49

// ---- two named load stages (20 regs each) ----
#define STAGE_DECL \
    float A_c0,A_c1,A_c2,A_c3,A_c4,A_c5,A_c6,A_c7,A_c8,A_c9, \
          A_p0,A_p1,A_p2,A_p3,A_p4,A_p5,A_p6,A_p7,A_p8,A_p9, \
          B_c0,B_c1,B_c2,B_c3,B_c4,B_c5,B_c6,B_c7,B_c8,B_c9, \
          B_p0,B_p1,B_p2,B_p3,B_p4,B_p5,B_p6,B_p7,B_p8,B_p9;

#define PF_(S, off) do { \
    const float* rp_ = xtc + (size_t)(trow + (off)) * DD; \
    const float* pp_ = xpc + (size_t)(trow + (off)) * DD; \
    S##c0 = rp_[0*DD]; S##c1 = rp_[1*DD]; S##c2 = rp_[2*DD]; S##c3 = rp_[3*DD]; S##c4 = rp_[4*DD]; \
    S##c5 = rp_[5*DD]; S##c6 = rp_[6*DD]; S##c7 = rp_[7*DD]; S##c8 = rp_[8*DD]; S##c9 = rp_[9*DD]; \
    S##p0 = NT(pp_+0*DD); S##p1 = NT(pp_+1*DD); S##p2 = NT(pp_+2*DD); S##p3 = NT(pp_+3*DD); S##p4 = NT(pp_+4*DD); \
    S##p5 = NT(pp_+5*DD); S##p6 = NT(pp_+6*DD); S##p7 = NT(pp_+7*DD); S##p8 = NT(pp_+8*DD); S##p9 = NT(pp_+9*DD); \
} while (0)
#define PFA(off) PF_(A_, off)
#define PFB(off) PF_(B_, off)

#define STEPC(pv, cv, R) { float e = (pv) - w * inv_n; acc += e * e; w += (cv) - (R); (R) = (cv); }

#define CONS_(S, Ra,Rb,Rc,Rd,Re,Rf,Rg,Rh,Ri,Rj) { \
    STEPC(S##p0, S##c0, Ra) STEPC(S##p1, S##c1, Rb) STEPC(S##p2, S##c2, Rc) \
    STEPC(S##p3, S##c3, Rd) STEPC(S##p4, S##c4, Re) STEPC(S##p5, S##c5, Rf) \
    STEPC(S##p6, S##c6, Rg) STEPC(S##p7, S##c7, Rh) STEPC(S##p8, S##c8, Ri) \
    STEPC(S##p9, S##c9, Rj) }
#define CONSX(S, ...) CONS_(S, __VA_ARGS__)
#define CONSA(RL) CONSX(A_, RL)
#define CONSB(RL) CONSX(B_, RL)

#define WARM0(t, R) { float cv = xtc[(size_t)(t)*DD]; float pv = xpc[(size_t)(t)*DD]; \
    float e = pv - (w + (float)(NLAG-(t)) * cv) * inv_n; acc += e * e; w += cv; (R) = cv; }

#define WLOAD(j, R) (R) = wsrc[(size_t)(j)*DD];

#define STEPT(i, R) { float cv = xtc[(size_t)(trow+(i))*DD]; float pv = xpc[(size_t)(trow+(i))*DD]; \
    float e = pv - w * inv_n; acc += e * e; w += cv - (R); (R) = cv; }

#define DO50(M) \
    M(0,R00) M(1,R01) M(2,R02) M(3,R03) M(4,R04) M(5,R05) M(6,R06) M(7,R07) M(8,R08) M(9,R09) \
    M(10,R10) M(11,R11) M(12,R12) M(13,R13) M(14,R14) M(15,R15) M(16,R16) M(17,R17) M(18,R18) M(19,R19) \
    M(20,R20) M(21,R21) M(22,R22) M(23,R23) M(24,R24) M(25,R25) M(26,R26) M(27,R27) M(28,R28) M(29,R29) \
    M(30,R30) M(31,R31) M(32,R32) M(33,R33) M(34,R34) M(35,R35) M(36,R36) M(37,R37) M(38,R38) M(39,R39) \
    M(40,R40) M(41,R41) M(42,R42) M(43,R43) M(44,R44) M(45,R45) M(46,R46) M(47,R47) M(48,R48) M(49,R49)

template <bool USE_WS>
__global__ __launch_bounds__(BLOCK, 3) void npdc_reg(
    const float* __restrict__ xp,
    const float* __restrict__ xt,
    float* __restrict__ partial,   // [RC][D] when USE_WS
    float* __restrict__ out)       // [D] atomic path when !USE_WS
{
    const int tid = (int)threadIdx.x;
    const int col = blockIdx.x * BLOCK + tid;
    const int rc  = blockIdx.y;
    const int r0  = rc * CHUNK;
    const float inv_n = 1.0f / (float)NLAG;

    const float* xtc = xt + col;
    const float* xpc = xp + col;

    RING_DECL
    STAGE_DECL
    float w = 0.f, acc = 0.f;
    int trow;

    if (rc == 0) {
        // rows 0..49: growing window (m = t); fills ring slots 0..49
        DO50(WARM0)
        trow = NLAG;
        // 10-batch pipeline: rows 50..149
        PFA(0);
        PFB(10); CONSA(RL0);
        PFA(20); CONSB(RL1);
        PFB(30); CONSA(RL2);
        PFA(40); CONSB(RL3);
        PFB(50); CONSA(RL4);
        PFA(60); CONSB(RL0);
        PFB(70); CONSA(RL1);
        PFA(80); CONSB(RL2);
        PFB(90); CONSA(RL3);
        CONSB(RL4);
    } else if (rc == RC - 1) {
        // last chunk: 34 rows. warm-up (parallel loads + tree sum), 3 batches + 4 tail
        const float* wsrc = xtc + (size_t)(r0 - NLAG) * DD;
        DO50(WLOAD)
        {
            float ta = ((R00+R01)+(R02+R03)) + ((R04+R05)+(R06+R07)) + (R08+R09);
            float tb = ((R10+R11)+(R12+R13)) + ((R14+R15)+(R16+R17)) + (R18+R19);
            float tc = ((R20+R21)+(R22+R23)) + ((R24+R25)+(R26+R27)) + (R28+R29);
            float td = ((R30+R31)+(R32+R33)) + ((R34+R35)+(R36+R37)) + (R38+R39);
            float te = ((R40+R41)+(R42+R43)) + ((R44+R45)+(R46+R47)) + (R48+R49);
            w = (ta + tb) + (tc + td) + te;
        }
        trow = r0;
        PFA(0);  CONSA(RL0);
        PFA(10); CONSA(RL1);
        PFA(20); CONSA(RL2);
        STEPT(30, R30) STEPT(31, R31) STEPT(32, R32) STEPT(33, R33)
    } else {
        // main chunks: warm-up (parallel loads + tree sum), 15-batch pipeline
        const float* wsrc = xtc + (size_t)(r0 - NLAG) * DD;
        DO50(WLOAD)
        {
            float ta = ((R00+R01)+(R02+R03)) + ((R04+R05)+(R06+R07)) + (R08+R09);
            float tb = ((R10+R11)+(R12+R13)) + ((R14+R15)+(R16+R17)) + (R18+R19);
            float tc = ((R20+R21)+(R22+R23)) + ((R24+R25)+(R26+R27)) + (R28+R29);
            float td = ((R30+R31)+(R32+R33)) + ((R34+R35)+(R36+R37)) + (R38+R39);
            float te = ((R40+R41)+(R42+R43)) + ((R44+R45)+(R46+R47)) + (R48+R49);
            w = (ta + tb) + (tc + td) + te;
        }
        trow = r0;
        PFA(0);
        PFB(10);  CONSA(RL0);
        PFA(20);  CONSB(RL1);
        PFB(30);  CONSA(RL2);
        PFA(40);  CONSB(RL3);
        PFB(50);  CONSA(RL4);
        PFA(60);  CONSB(RL0);
        PFB(70);  CONSA(RL1);
        PFA(80);  CONSB(RL2);
        PFB(90);  CONSA(RL3);
        PFA(100); CONSB(RL4);
        PFB(110); CONSA(RL0);
        PFA(120); CONSB(RL1);
        PFB(130); CONSA(RL2);
        PFA(140); CONSB(RL3);
        CONSA(RL4);
    }

    if (USE_WS) {
        partial[(size_t)rc * DD + col] = acc;
    } else {
        atomicAdd(&out[col], acc * (1.0f / (float)NS));
    }
}

// Reduce [RC][D] -> [D].  Grid: D/64 blocks of 256 threads.
__global__ __launch_bounds__(BLOCK) void npdc_reduce(
    const float* __restrict__ partial, float* __restrict__ out)
{
    const int dl = (int)threadIdx.x & 63;
    const int g  = (int)threadIdx.x >> 6;          // 0..3
    const int d  = blockIdx.x * 64 + dl;
    const int c0 = g * 28;
    const int c1 = (c0 + 28 < RC) ? c0 + 28 : RC;

    float s = 0.0f;
    for (int c = c0; c < c1; ++c)
        s += partial[(size_t)c * DD + d];

    __shared__ float sm[4][64];
    sm[g][dl] = s;
    __syncthreads();
    if (g == 0) {
        float t = sm[0][dl] + sm[1][dl] + sm[2][dl] + sm[3][dl];
        out[d] = t * (1.0f / (float)NS);
    }
}

__global__ __launch_bounds__(BLOCK) void npdc_zero(float* __restrict__ out)
{
    const int d = blockIdx.x * BLOCK + (int)threadIdx.x;
    if (d < D) out[d] = 0.0f;
}

extern "C" void kernel_launch(void* const* d_in, const int* in_sizes, int n_in,
                              void* d_out, int out_size, void* d_ws, size_t ws_size,
                              hipStream_t stream)
{
    const float* xp = (const float*)d_in[0];   // x_pred [NS, D]
    const float* xt = (const float*)d_in[1];   // x_true [NS, D]
    float* out = (float*)d_out;                // [D]

    const size_t ws_needed = (size_t)RC * D * sizeof(float);
    dim3 grid(COLB, RC);

    if (ws_size >= ws_needed) {
        float* partial = (float*)d_ws;
        npdc_reg<true><<<grid, BLOCK, 0, stream>>>(xp, xt, partial, out);
        npdc_reduce<<<D / 64, BLOCK, 0, stream>>>(partial, out);
    } else {
        npdc_zero<<<(D + BLOCK - 1) / BLOCK, BLOCK, 0, stream>>>(out);
        npdc_reg<false><<<grid, BLOCK, 0, stream>>>(xp, xt, nullptr, out);
    }
}

// Round 11
// 56.635 us; speedup vs baseline: 1.1650x; 1.0391x over previous
//
#include <hip/hip_runtime.h>
#include <stddef.h>

// NPDCLoss: out[d] = mean_t (x_pred[t,d] - delayed_avg[t,d])^2
//   delayed_avg[t] = (sum_{j=1..m} x_true[t-j] + (NLAG-m)*x_true[t]) / NLAG
// Lag-50 window in 50 NAMED float2 registers (2 columns/thread -> 512 B
// requests per wave). Single 10-row load stage (20 float2 loads in flight).

#define NS   16384
#define D    2048
#define NLAG 50

#define BLOCK 256
#define CPT   2                      // columns per thread
#define COLB  (D / (BLOCK * CPT))    // 4 column blocks
#define CHUNK 100                    // rows per chunk
#define RC    164                    // 163 full chunks + last chunk of 84 rows

#define DD ((size_t)D)

typedef float f2 __attribute__((ext_vector_type(2)));

__device__ __forceinline__ f2 ld2(const float* p) {
    return *reinterpret_cast<const f2*>(p);
}
__device__ __forceinline__ f2 ld2nt(const float* p) {
    return __builtin_nontemporal_load(reinterpret_cast<const f2*>(p));
}

// ---- the 50-register float2 ring ----
#define RING_DECL \
    f2 R00,R01,R02,R03,R04,R05,R06,R07,R08,R09, \
       R10,R11,R12,R13,R14,R15,R16,R17,R18,R19, \
       R20,R21,R22,R23,R24,R25,R26,R27,R28,R29, \
       R30,R31,R32,R33,R34,R35,R36,R37,R38,R39, \
       R40,R41,R42,R43,R44,R45,R46,R47,R48,R49;

#define RL0 R00,R01,R02,R03,R04,R05,R06,R07,R08,R09
#define RL1 R10,R11,R12,R13,R14,R15,R16,R17,R18,R19
#define RL2 R20,R21,R22,R23,R24,R25,R26,R27,R28,R29
#define RL3 R30,R31,R32,R33,R34,R35,R36,R37,R38,R39
#define RL4 R40,R41,R42,R43,R44,R45,R46,R47,R48,R49

#define STEPC(pv, cv, R) { f2 e = (pv) - w * inv_n; acc += e * e; w += (cv) - (R); (R) = (cv); }

// one 10-row batch: 20 float2 loads issued, then 10 compute steps
#define C10_IMPL(Ra,Rb,Rc,Rd,Re,Rf,Rg,Rh,Ri,Rj) do { \
    const float* rp = xtc + (size_t)trow * DD; \
    const float* pp = xpc + (size_t)trow * DD; \
    f2 c0=ld2(rp+0*DD), c1=ld2(rp+1*DD), c2=ld2(rp+2*DD), c3=ld2(rp+3*DD), c4=ld2(rp+4*DD), \
       c5=ld2(rp+5*DD), c6=ld2(rp+6*DD), c7=ld2(rp+7*DD), c8=ld2(rp+8*DD), c9=ld2(rp+9*DD); \
    f2 p0=ld2nt(pp+0*DD), p1=ld2nt(pp+1*DD), p2=ld2nt(pp+2*DD), p3=ld2nt(pp+3*DD), p4=ld2nt(pp+4*DD), \
       p5=ld2nt(pp+5*DD), p6=ld2nt(pp+6*DD), p7=ld2nt(pp+7*DD), p8=ld2nt(pp+8*DD), p9=ld2nt(pp+9*DD); \
    STEPC(p0,c0,Ra) STEPC(p1,c1,Rb) STEPC(p2,c2,Rc) STEPC(p3,c3,Rd) STEPC(p4,c4,Re) \
    STEPC(p5,c5,Rf) STEPC(p6,c6,Rg) STEPC(p7,c7,Rh) STEPC(p8,c8,Ri) STEPC(p9,c9,Rj) \
    trow += 10; \
} while (0)
#define C10(...) C10_IMPL(__VA_ARGS__)

#define WARM0(t, R) { f2 cv = ld2(&xtc[(size_t)(t)*DD]); f2 pv = ld2nt(&xpc[(size_t)(t)*DD]); \
    f2 e = pv - (w + (float)(NLAG-(t)) * cv) * inv_n; acc += e * e; w += cv; (R) = cv; }

#define WLOAD(j, R) (R) = ld2(&wsrc[(size_t)(j)*DD]);

// tail step using ring register (slot = hot index % 50)
#define STEPT(i, R) { f2 cv = ld2(&xtc[(size_t)(trow+(i))*DD]); f2 pv = ld2nt(&xpc[(size_t)(trow+(i))*DD]); \
    f2 e = pv - w * inv_n; acc += e * e; w += cv - (R); (R) = cv; }

#define DO50(M) \
    M(0,R00) M(1,R01) M(2,R02) M(3,R03) M(4,R04) M(5,R05) M(6,R06) M(7,R07) M(8,R08) M(9,R09) \
    M(10,R10) M(11,R11) M(12,R12) M(13,R13) M(14,R14) M(15,R15) M(16,R16) M(17,R17) M(18,R18) M(19,R19) \
    M(20,R20) M(21,R21) M(22,R22) M(23,R23) M(24,R24) M(25,R25) M(26,R26) M(27,R27) M(28,R28) M(29,R29) \
    M(30,R30) M(31,R31) M(32,R32) M(33,R33) M(34,R34) M(35,R35) M(36,R36) M(37,R37) M(38,R38) M(39,R39) \
    M(40,R40) M(41,R41) M(42,R42) M(43,R43) M(44,R44) M(45,R45) M(46,R46) M(47,R47) M(48,R48) M(49,R49)

#define TREESUM_W { \
    f2 ta = ((R00+R01)+(R02+R03)) + ((R04+R05)+(R06+R07)) + (R08+R09); \
    f2 tb = ((R10+R11)+(R12+R13)) + ((R14+R15)+(R16+R17)) + (R18+R19); \
    f2 tc = ((R20+R21)+(R22+R23)) + ((R24+R25)+(R26+R27)) + (R28+R29); \
    f2 td = ((R30+R31)+(R32+R33)) + ((R34+R35)+(R36+R37)) + (R38+R39); \
    f2 te = ((R40+R41)+(R42+R43)) + ((R44+R45)+(R46+R47)) + (R48+R49); \
    w = (ta + tb) + (tc + td) + te; }

template <bool USE_WS>
__global__ __launch_bounds__(BLOCK, 2) void npdc_reg(
    const float* __restrict__ xp,
    const float* __restrict__ xt,
    float* __restrict__ partial,   // [RC][D] when USE_WS
    float* __restrict__ out)       // [D] atomic path when !USE_WS
{
    const int tid = (int)threadIdx.x;
    const int col = blockIdx.x * (BLOCK * CPT) + tid * CPT;
    const int rc  = blockIdx.y;
    const int r0  = rc * CHUNK;
    const float inv_n = 1.0f / (float)NLAG;

    const float* xtc = xt + col;
    const float* xpc = xp + col;

    RING_DECL
    f2 w = (f2)0.f, acc = (f2)0.f;
    int trow;

    if (rc == 0) {
        // rows 0..49: growing window (m = t); fills ring slots 0..49
        DO50(WARM0)
        trow = NLAG;
        // hot rows 50..99: 5 batches
        C10(RL0); C10(RL1); C10(RL2); C10(RL3); C10(RL4);
    } else if (rc == RC - 1) {
        // last chunk: 84 rows = 8 batches + 4 tail (slots 30..33)
        const float* wsrc = xtc + (size_t)(r0 - NLAG) * DD;
        DO50(WLOAD)
        TREESUM_W
        trow = r0;
        C10(RL0); C10(RL1); C10(RL2); C10(RL3); C10(RL4);
        C10(RL0); C10(RL1); C10(RL2);
        STEPT(0, R30) STEPT(1, R31) STEPT(2, R32) STEPT(3, R33)
    } else {
        // main chunks: parallel warm-up, 10 batches (hot = 100 rows)
        const float* wsrc = xtc + (size_t)(r0 - NLAG) * DD;
        DO50(WLOAD)
        TREESUM_W
        trow = r0;
        C10(RL0); C10(RL1); C10(RL2); C10(RL3); C10(RL4);
        C10(RL0); C10(RL1); C10(RL2); C10(RL3); C10(RL4);
    }

    if (USE_WS) {
        *reinterpret_cast<f2*>(&partial[(size_t)rc * DD + col]) = acc;
    } else {
        const float inv_ns = 1.0f / (float)NS;
        atomicAdd(&out[col],     acc.x * inv_ns);
        atomicAdd(&out[col + 1], acc.y * inv_ns);
    }
}

// Reduce [RC][D] -> [D].  Grid: D/64 blocks of 256 threads.
__global__ __launch_bounds__(BLOCK) void npdc_reduce(
    const float* __restrict__ partial, float* __restrict__ out)
{
    const int dl = (int)threadIdx.x & 63;
    const int g  = (int)threadIdx.x >> 6;          // 0..3
    const int d  = blockIdx.x * 64 + dl;
    const int c0 = g * (RC / 4);

    float s = 0.0f;
    for (int c = c0; c < c0 + RC / 4; ++c)
        s += partial[(size_t)c * DD + d];

    __shared__ float sm[4][64];
    sm[g][dl] = s;
    __syncthreads();
    if (g == 0) {
        float t = sm[0][dl] + sm[1][dl] + sm[2][dl] + sm[3][dl];
        out[d] = t * (1.0f / (float)NS);
    }
}

__global__ __launch_bounds__(BLOCK) void npdc_zero(float* __restrict__ out)
{
    const int d = blockIdx.x * BLOCK + (int)threadIdx.x;
    if (d < D) out[d] = 0.0f;
}

extern "C" void kernel_launch(void* const* d_in, const int* in_sizes, int n_in,
                              void* d_out, int out_size, void* d_ws, size_t ws_size,
                              hipStream_t stream)
{
    const float* xp = (const float*)d_in[0];   // x_pred [NS, D]
    const float* xt = (const float*)d_in[1];   // x_true [NS, D]
    float* out = (float*)d_out;                // [D]

    const size_t ws_needed = (size_t)RC * D * sizeof(float);
    dim3 grid(COLB, RC);

    if (ws_size >= ws_needed) {
        float* partial = (float*)d_ws;
        npdc_reg<true><<<grid, BLOCK, 0, stream>>>(xp, xt, partial, out);
        npdc_reduce<<<D / 64, BLOCK, 0, stream>>>(partial, out);
    } else {
        npdc_zero<<<(D + BLOCK - 1) / BLOCK, BLOCK, 0, stream>>>(out);
        npdc_reg<false><<<grid, BLOCK, 0, stream>>>(xp, xt, nullptr, out);
    }
}

// Round 12
// 52.066 us; speedup vs baseline: 1.2672x; 1.0878x over previous
//
#include <hip/hip_runtime.h>
#include <stddef.h>

// NPDCLoss: out[d] = mean_t (x_pred[t,d] - delayed_avg[t,d])^2
//   delayed_avg[t] = (sum_{j=1..m} x_true[t-j] + (NLAG-m)*x_true[t]) / NLAG
// Lag-50 window in 50 NAMED float2 registers (2 columns/thread -> 512 B
// requests per wave). CHUNK=128: NS/128=128 chunks exactly, grid=512 blocks
// = 2 blocks/CU balanced; warm-up traffic 52 MB (total ~308 MB demand).

#define NS   16384
#define D    2048
#define NLAG 50

#define BLOCK 256
#define CPT   2                      // columns per thread
#define COLB  (D / (BLOCK * CPT))    // 4 column blocks
#define CHUNK 128                    // rows per chunk (NS/CHUNK = 128, no tail)
#define RC    (NS / CHUNK)           // 128

#define DD ((size_t)D)

typedef float f2 __attribute__((ext_vector_type(2)));

__device__ __forceinline__ f2 ld2(const float* p) {
    return *reinterpret_cast<const f2*>(p);
}
__device__ __forceinline__ f2 ld2nt(const float* p) {
    return __builtin_nontemporal_load(reinterpret_cast<const f2*>(p));
}

// ---- the 50-register float2 ring ----
#define RING_DECL \
    f2 R00,R01,R02,R03,R04,R05,R06,R07,R08,R09, \
       R10,R11,R12,R13,R14,R15,R16,R17,R18,R19, \
       R20,R21,R22,R23,R24,R25,R26,R27,R28,R29, \
       R30,R31,R32,R33,R34,R35,R36,R37,R38,R39, \
       R40,R41,R42,R43,R44,R45,R46,R47,R48,R49;

#define RL0 R00,R01,R02,R03,R04,R05,R06,R07,R08,R09
#define RL1 R10,R11,R12,R13,R14,R15,R16,R17,R18,R19
#define RL2 R20,R21,R22,R23,R24,R25,R26,R27,R28,R29
#define RL3 R30,R31,R32,R33,R34,R35,R36,R37,R38,R39
#define RL4 R40,R41,R42,R43,R44,R45,R46,R47,R48,R49

#define STEPC(pv, cv, R) { f2 e = (pv) - w * inv_n; acc += e * e; w += (cv) - (R); (R) = (cv); }

// one 10-row batch: 20 float2 loads issued, then 10 compute steps
#define C10_IMPL(Ra,Rb,Rc,Rd,Re,Rf,Rg,Rh,Ri,Rj) do { \
    const float* rp = xtc + (size_t)trow * DD; \
    const float* pp = xpc + (size_t)trow * DD; \
    f2 c0=ld2(rp+0*DD), c1=ld2(rp+1*DD), c2=ld2(rp+2*DD), c3=ld2(rp+3*DD), c4=ld2(rp+4*DD), \
       c5=ld2(rp+5*DD), c6=ld2(rp+6*DD), c7=ld2(rp+7*DD), c8=ld2(rp+8*DD), c9=ld2(rp+9*DD); \
    f2 p0=ld2nt(pp+0*DD), p1=ld2nt(pp+1*DD), p2=ld2nt(pp+2*DD), p3=ld2nt(pp+3*DD), p4=ld2nt(pp+4*DD), \
       p5=ld2nt(pp+5*DD), p6=ld2nt(pp+6*DD), p7=ld2nt(pp+7*DD), p8=ld2nt(pp+8*DD), p9=ld2nt(pp+9*DD); \
    STEPC(p0,c0,Ra) STEPC(p1,c1,Rb) STEPC(p2,c2,Rc) STEPC(p3,c3,Rd) STEPC(p4,c4,Re) \
    STEPC(p5,c5,Rf) STEPC(p6,c6,Rg) STEPC(p7,c7,Rh) STEPC(p8,c8,Ri) STEPC(p9,c9,Rj) \
    trow += 10; \
} while (0)
#define C10(...) C10_IMPL(__VA_ARGS__)

// one 8-row batch on ring slots 20..27 (hot index ≡ 20 mod 50)
#define C8_2027 do { \
    const float* rp = xtc + (size_t)trow * DD; \
    const float* pp = xpc + (size_t)trow * DD; \
    f2 c0=ld2(rp+0*DD), c1=ld2(rp+1*DD), c2=ld2(rp+2*DD), c3=ld2(rp+3*DD), \
       c4=ld2(rp+4*DD), c5=ld2(rp+5*DD), c6=ld2(rp+6*DD), c7=ld2(rp+7*DD); \
    f2 p0=ld2nt(pp+0*DD), p1=ld2nt(pp+1*DD), p2=ld2nt(pp+2*DD), p3=ld2nt(pp+3*DD), \
       p4=ld2nt(pp+4*DD), p5=ld2nt(pp+5*DD), p6=ld2nt(pp+6*DD), p7=ld2nt(pp+7*DD); \
    STEPC(p0,c0,R20) STEPC(p1,c1,R21) STEPC(p2,c2,R22) STEPC(p3,c3,R23) \
    STEPC(p4,c4,R24) STEPC(p5,c5,R25) STEPC(p6,c6,R26) STEPC(p7,c7,R27) \
    trow += 8; \
} while (0)

#define WARM0(t, R) { f2 cv = ld2(&xtc[(size_t)(t)*DD]); f2 pv = ld2nt(&xpc[(size_t)(t)*DD]); \
    f2 e = pv - (w + (float)(NLAG-(t)) * cv) * inv_n; acc += e * e; w += cv; (R) = cv; }

#define WLOAD(j, R) (R) = ld2(&wsrc[(size_t)(j)*DD]);

#define DO50(M) \
    M(0,R00) M(1,R01) M(2,R02) M(3,R03) M(4,R04) M(5,R05) M(6,R06) M(7,R07) M(8,R08) M(9,R09) \
    M(10,R10) M(11,R11) M(12,R12) M(13,R13) M(14,R14) M(15,R15) M(16,R16) M(17,R17) M(18,R18) M(19,R19) \
    M(20,R20) M(21,R21) M(22,R22) M(23,R23) M(24,R24) M(25,R25) M(26,R26) M(27,R27) M(28,R28) M(29,R29) \
    M(30,R30) M(31,R31) M(32,R32) M(33,R33) M(34,R34) M(35,R35) M(36,R36) M(37,R37) M(38,R38) M(39,R39) \
    M(40,R40) M(41,R41) M(42,R42) M(43,R43) M(44,R44) M(45,R45) M(46,R46) M(47,R47) M(48,R48) M(49,R49)

#define TREESUM_W { \
    f2 ta = ((R00+R01)+(R02+R03)) + ((R04+R05)+(R06+R07)) + (R08+R09); \
    f2 tb = ((R10+R11)+(R12+R13)) + ((R14+R15)+(R16+R17)) + (R18+R19); \
    f2 tc = ((R20+R21)+(R22+R23)) + ((R24+R25)+(R26+R27)) + (R28+R29); \
    f2 td = ((R30+R31)+(R32+R33)) + ((R34+R35)+(R36+R37)) + (R38+R39); \
    f2 te = ((R40+R41)+(R42+R43)) + ((R44+R45)+(R46+R47)) + (R48+R49); \
    w = (ta + tb) + (tc + td) + te; }

template <bool USE_WS>
__global__ __launch_bounds__(BLOCK, 2) void npdc_reg(
    const float* __restrict__ xp,
    const float* __restrict__ xt,
    float* __restrict__ partial,   // [RC][D] when USE_WS
    float* __restrict__ out)       // [D] atomic path when !USE_WS
{
    const int tid = (int)threadIdx.x;
    const int col = blockIdx.x * (BLOCK * CPT) + tid * CPT;
    const int rc  = blockIdx.y;
    const int r0  = rc * CHUNK;
    const float inv_n = 1.0f / (float)NLAG;

    const float* xtc = xt + col;
    const float* xpc = xp + col;

    RING_DECL
    f2 w = (f2)0.f, acc = (f2)0.f;
    int trow;

    if (rc == 0) {
        // rows 0..49: growing window (m = t); fills ring slots 0..49.
        DO50(WARM0)
        trow = NLAG;
        // hot rows 50..127: 78 rows = 7 batches (slots 0..69%50) + 8 @ slots 20..27
        C10(RL0); C10(RL1); C10(RL2); C10(RL3); C10(RL4);
        C10(RL0); C10(RL1);
        C8_2027;
    } else {
        // warm-up rows r0-50..r0-1 -> slots 0..49 (parallel loads + tree sum)
        const float* wsrc = xtc + (size_t)(r0 - NLAG) * DD;
        DO50(WLOAD)
        TREESUM_W
        trow = r0;
        // hot: 128 rows = 12 C10 batches (120) + 8 @ slots 20..27
        C10(RL0); C10(RL1); C10(RL2); C10(RL3); C10(RL4);
        C10(RL0); C10(RL1); C10(RL2); C10(RL3); C10(RL4);
        C10(RL0); C10(RL1);
        C8_2027;
    }

    if (USE_WS) {
        *reinterpret_cast<f2*>(&partial[(size_t)rc * DD + col]) = acc;
    } else {
        const float inv_ns = 1.0f / (float)NS;
        atomicAdd(&out[col],     acc.x * inv_ns);
        atomicAdd(&out[col + 1], acc.y * inv_ns);
    }
}

// Reduce [RC][D] -> [D].  Grid: D/64 blocks of 256 threads.
__global__ __launch_bounds__(BLOCK) void npdc_reduce(
    const float* __restrict__ partial, float* __restrict__ out)
{
    const int dl = (int)threadIdx.x & 63;
    const int g  = (int)threadIdx.x >> 6;          // 0..3
    const int d  = blockIdx.x * 64 + dl;
    const int c0 = g * (RC / 4);

    float s = 0.0f;
    #pragma unroll 8
    for (int c = c0; c < c0 + RC / 4; ++c)
        s += partial[(size_t)c * DD + d];

    __shared__ float sm[4][64];
    sm[g][dl] = s;
    __syncthreads();
    if (g == 0) {
        float t = sm[0][dl] + sm[1][dl] + sm[2][dl] + sm[3][dl];
        out[d] = t * (1.0f / (float)NS);
    }
}

__global__ __launch_bounds__(BLOCK) void npdc_zero(float* __restrict__ out)
{
    const int d = blockIdx.x * BLOCK + (int)threadIdx.x;
    if (d < D) out[d] = 0.0f;
}

extern "C" void kernel_launch(void* const* d_in, const int* in_sizes, int n_in,
                              void* d_out, int out_size, void* d_ws, size_t ws_size,
                              hipStream_t stream)
{
    const float* xp = (const float*)d_in[0];   // x_pred [NS, D]
    const float* xt = (const float*)d_in[1];   // x_true [NS, D]
    float* out = (float*)d_out;                // [D]

    const size_t ws_needed = (size_t)RC * D * sizeof(float);
    dim3 grid(COLB, RC);

    if (ws_size >= ws_needed) {
        float* partial = (float*)d_ws;
        npdc_reg<true><<<grid, BLOCK, 0, stream>>>(xp, xt, partial, out);
        npdc_reduce<<<D / 64, BLOCK, 0, stream>>>(partial, out);
    } else {
        npdc_zero<<<(D + BLOCK - 1) / BLOCK, BLOCK, 0, stream>>>(out);
        npdc_reg<false><<<grid, BLOCK, 0, stream>>>(xp, xt, nullptr, out);
    }
}

// Round 13
// 50.304 us; speedup vs baseline: 1.3116x; 1.0350x over previous
//
#include <hip/hip_runtime.h>
#include <stddef.h>

// NPDCLoss: out[d] = mean_t (x_pred[t,d] - delayed_avg[t,d])^2
//   delayed_avg[t] = (sum_{j=1..m} x_true[t-j] + (NLAG-m)*x_true[t]) / NLAG
// Lag-50 window in 50 NAMED float2 registers (2 columns/thread -> 512 B
// requests per wave). CHUNK=256: RC=64 chunks, grid=256 blocks = 1/CU,
// warm-up traffic 26 MB (total ~282 MB demand ~= 1.10x compulsory).

#define NS   16384
#define D    2048
#define NLAG 50

#define BLOCK 256
#define CPT   2                      // columns per thread
#define COLB  (D / (BLOCK * CPT))    // 4 column blocks
#define CHUNK 256                    // rows per chunk (NS/CHUNK = 64, no tail)
#define RC    (NS / CHUNK)           // 64

#define DD ((size_t)D)

typedef float f2 __attribute__((ext_vector_type(2)));

__device__ __forceinline__ f2 ld2(const float* p) {
    return *reinterpret_cast<const f2*>(p);
}
__device__ __forceinline__ f2 ld2nt(const float* p) {
    return __builtin_nontemporal_load(reinterpret_cast<const f2*>(p));
}

// ---- the 50-register float2 ring ----
#define RING_DECL \
    f2 R00,R01,R02,R03,R04,R05,R06,R07,R08,R09, \
       R10,R11,R12,R13,R14,R15,R16,R17,R18,R19, \
       R20,R21,R22,R23,R24,R25,R26,R27,R28,R29, \
       R30,R31,R32,R33,R34,R35,R36,R37,R38,R39, \
       R40,R41,R42,R43,R44,R45,R46,R47,R48,R49;

#define RL0 R00,R01,R02,R03,R04,R05,R06,R07,R08,R09
#define RL1 R10,R11,R12,R13,R14,R15,R16,R17,R18,R19
#define RL2 R20,R21,R22,R23,R24,R25,R26,R27,R28,R29
#define RL3 R30,R31,R32,R33,R34,R35,R36,R37,R38,R39
#define RL4 R40,R41,R42,R43,R44,R45,R46,R47,R48,R49

#define STEPC(pv, cv, R) { f2 e = (pv) - w * inv_n; acc += e * e; w += (cv) - (R); (R) = (cv); }

// one 10-row batch: 20 float2 loads issued, then 10 compute steps
#define C10_IMPL(Ra,Rb,Rc,Rd,Re,Rf,Rg,Rh,Ri,Rj) do { \
    const float* rp = xtc + (size_t)trow * DD; \
    const float* pp = xpc + (size_t)trow * DD; \
    f2 c0=ld2(rp+0*DD), c1=ld2(rp+1*DD), c2=ld2(rp+2*DD), c3=ld2(rp+3*DD), c4=ld2(rp+4*DD), \
       c5=ld2(rp+5*DD), c6=ld2(rp+6*DD), c7=ld2(rp+7*DD), c8=ld2(rp+8*DD), c9=ld2(rp+9*DD); \
    f2 p0=ld2nt(pp+0*DD), p1=ld2nt(pp+1*DD), p2=ld2nt(pp+2*DD), p3=ld2nt(pp+3*DD), p4=ld2nt(pp+4*DD), \
       p5=ld2nt(pp+5*DD), p6=ld2nt(pp+6*DD), p7=ld2nt(pp+7*DD), p8=ld2nt(pp+8*DD), p9=ld2nt(pp+9*DD); \
    STEPC(p0,c0,Ra) STEPC(p1,c1,Rb) STEPC(p2,c2,Rc) STEPC(p3,c3,Rd) STEPC(p4,c4,Re) \
    STEPC(p5,c5,Rf) STEPC(p6,c6,Rg) STEPC(p7,c7,Rh) STEPC(p8,c8,Ri) STEPC(p9,c9,Rj) \
    trow += 10; \
} while (0)
#define C10(...) C10_IMPL(__VA_ARGS__)

// one 6-row batch on ring slots 0..5 (hot index ≡ 0 mod 50)
#define C6_0005 do { \
    const float* rp = xtc + (size_t)trow * DD; \
    const float* pp = xpc + (size_t)trow * DD; \
    f2 c0=ld2(rp+0*DD), c1=ld2(rp+1*DD), c2=ld2(rp+2*DD), \
       c3=ld2(rp+3*DD), c4=ld2(rp+4*DD), c5=ld2(rp+5*DD); \
    f2 p0=ld2nt(pp+0*DD), p1=ld2nt(pp+1*DD), p2=ld2nt(pp+2*DD), \
       p3=ld2nt(pp+3*DD), p4=ld2nt(pp+4*DD), p5=ld2nt(pp+5*DD); \
    STEPC(p0,c0,R00) STEPC(p1,c1,R01) STEPC(p2,c2,R02) \
    STEPC(p3,c3,R03) STEPC(p4,c4,R04) STEPC(p5,c5,R05) \
    trow += 6; \
} while (0)

#define WARM0(t, R) { f2 cv = ld2(&xtc[(size_t)(t)*DD]); f2 pv = ld2nt(&xpc[(size_t)(t)*DD]); \
    f2 e = pv - (w + (float)(NLAG-(t)) * cv) * inv_n; acc += e * e; w += cv; (R) = cv; }

#define WLOAD(j, R) (R) = ld2(&wsrc[(size_t)(j)*DD]);

#define DO50(M) \
    M(0,R00) M(1,R01) M(2,R02) M(3,R03) M(4,R04) M(5,R05) M(6,R06) M(7,R07) M(8,R08) M(9,R09) \
    M(10,R10) M(11,R11) M(12,R12) M(13,R13) M(14,R14) M(15,R15) M(16,R16) M(17,R17) M(18,R18) M(19,R19) \
    M(20,R20) M(21,R21) M(22,R22) M(23,R23) M(24,R24) M(25,R25) M(26,R26) M(27,R27) M(28,R28) M(29,R29) \
    M(30,R30) M(31,R31) M(32,R32) M(33,R33) M(34,R34) M(35,R35) M(36,R36) M(37,R37) M(38,R38) M(39,R39) \
    M(40,R40) M(41,R41) M(42,R42) M(43,R43) M(44,R44) M(45,R45) M(46,R46) M(47,R47) M(48,R48) M(49,R49)

#define TREESUM_W { \
    f2 ta = ((R00+R01)+(R02+R03)) + ((R04+R05)+(R06+R07)) + (R08+R09); \
    f2 tb = ((R10+R11)+(R12+R13)) + ((R14+R15)+(R16+R17)) + (R18+R19); \
    f2 tc = ((R20+R21)+(R22+R23)) + ((R24+R25)+(R26+R27)) + (R28+R29); \
    f2 td = ((R30+R31)+(R32+R33)) + ((R34+R35)+(R36+R37)) + (R38+R39); \
    f2 te = ((R40+R41)+(R42+R43)) + ((R44+R45)+(R46+R47)) + (R48+R49); \
    w = (ta + tb) + (tc + td) + te; }

#define HOT5X  { C10(RL0); C10(RL1); C10(RL2); C10(RL3); C10(RL4); }

template <bool USE_WS>
__global__ __launch_bounds__(BLOCK, 1) void npdc_reg(
    const float* __restrict__ xp,
    const float* __restrict__ xt,
    float* __restrict__ partial,   // [RC][D] when USE_WS
    float* __restrict__ out)       // [D] atomic path when !USE_WS
{
    const int tid = (int)threadIdx.x;
    const int col = blockIdx.x * (BLOCK * CPT) + tid * CPT;
    const int rc  = blockIdx.y;
    const int r0  = rc * CHUNK;
    const float inv_n = 1.0f / (float)NLAG;

    const float* xtc = xt + col;
    const float* xpc = xp + col;

    RING_DECL
    f2 w = (f2)0.f, acc = (f2)0.f;
    int trow;

    if (rc == 0) {
        // rows 0..49: growing window (m = t); fills ring slots 0..49.
        DO50(WARM0)
        trow = NLAG;
        // hot rows 50..255: 206 rows = 20 C10 (4 full RL cycles) + 6 @ slots 0..5
        HOT5X HOT5X HOT5X HOT5X
        C6_0005;
    } else {
        // warm-up rows r0-50..r0-1 -> slots 0..49 (parallel loads + tree sum)
        const float* wsrc = xtc + (size_t)(r0 - NLAG) * DD;
        DO50(WLOAD)
        TREESUM_W
        trow = r0;
        // hot: 256 rows = 25 C10 (5 full RL cycles) + 6 @ slots 0..5
        HOT5X HOT5X HOT5X HOT5X HOT5X
        C6_0005;
    }

    if (USE_WS) {
        *reinterpret_cast<f2*>(&partial[(size_t)rc * DD + col]) = acc;
    } else {
        const float inv_ns = 1.0f / (float)NS;
        atomicAdd(&out[col],     acc.x * inv_ns);
        atomicAdd(&out[col + 1], acc.y * inv_ns);
    }
}

// Reduce [RC][D] -> [D].  Grid: D/64 blocks of 256 threads.
__global__ __launch_bounds__(BLOCK) void npdc_reduce(
    const float* __restrict__ partial, float* __restrict__ out)
{
    const int dl = (int)threadIdx.x & 63;
    const int g  = (int)threadIdx.x >> 6;          // 0..3
    const int d  = blockIdx.x * 64 + dl;
    const int c0 = g * (RC / 4);

    float s = 0.0f;
    #pragma unroll 8
    for (int c = c0; c < c0 + RC / 4; ++c)
        s += partial[(size_t)c * DD + d];

    __shared__ float sm[4][64];
    sm[g][dl] = s;
    __syncthreads();
    if (g == 0) {
        float t = sm[0][dl] + sm[1][dl] + sm[2][dl] + sm[3][dl];
        out[d] = t * (1.0f / (float)NS);
    }
}

__global__ __launch_bounds__(BLOCK) void npdc_zero(float* __restrict__ out)
{
    const int d = blockIdx.x * BLOCK + (int)threadIdx.x;
    if (d < D) out[d] = 0.0f;
}

extern "C" void kernel_launch(void* const* d_in, const int* in_sizes, int n_in,
                              void* d_out, int out_size, void* d_ws, size_t ws_size,
                              hipStream_t stream)
{
    const float* xp = (const float*)d_in[0];   // x_pred [NS, D]
    const float* xt = (const float*)d_in[1];   // x_true [NS, D]
    float* out = (float*)d_out;                // [D]

    const size_t ws_needed = (size_t)RC * D * sizeof(float);
    dim3 grid(COLB, RC);

    if (ws_size >= ws_needed) {
        float* partial = (float*)d_ws;
        npdc_reg<true><<<grid, BLOCK, 0, stream>>>(xp, xt, partial, out);
        npdc_reduce<<<D / 64, BLOCK, 0, stream>>>(partial, out);
    } else {
        npdc_zero<<<(D + BLOCK - 1) / BLOCK, BLOCK, 0, stream>>>(out);
        npdc_reg<false><<<grid, BLOCK, 0, stream>>>(xp, xt, nullptr, out);
    }
}